// Round 7
// baseline (1482.693 us; speedup 1.0000x reference)
//
#include <hip/hip_runtime.h>
#include <hip/hip_cooperative_groups.h>
#include <stdint.h>

namespace cg = cooperative_groups;

#define B_SZ 128
#define T_SZ 64
#define N_IN 1024
#define N_HID 4096
#define N_OUT 1024
#define TAU 0.9f
#define THRESH 0.5f
#define REC_SCALE 0.1f
#define S_DENSE 6          // steps 0..5 computed via dense MFMA GEMMs
#define KSPLIT 8           // K-split for spk GEMMs (4096/8 = 512 per chunk)

typedef __attribute__((ext_vector_type(8))) short sh8;
typedef __attribute__((ext_vector_type(4))) float f32x4;
typedef __attribute__((ext_vector_type(4))) unsigned short ush4;
typedef __attribute__((ext_vector_type(8))) unsigned short ush8;

// ---------------------------------------------------------------------------
// helpers
// ---------------------------------------------------------------------------
__device__ __forceinline__ unsigned short f2bf_rn(float f) {
    unsigned u = __float_as_uint(f);
    unsigned r = (u + 0x7FFFu + ((u >> 16) & 1u)) >> 16;
    return (unsigned short)r;
}
__device__ __forceinline__ float bf2f(unsigned short h) {
    return __uint_as_float((unsigned)h << 16);
}
__device__ __forceinline__ void gload_lds16(const void* g, void* l) {
    __builtin_amdgcn_global_load_lds(
        (const __attribute__((address_space(1))) void*)g,
        (__attribute__((address_space(3))) void*)l, 16, 0, 0);
}
// compress low nibbles of 4 bytes into 16 bits
__device__ __forceinline__ unsigned pack4(unsigned a) {
    a &= 0x0F0F0F0Fu;
    a = (a | (a >> 4)) & 0x00FF00FFu;
    a = (a | (a >> 8)) & 0x0000FFFFu;
    return a;
}

// ---------------------------------------------------------------------------
__global__ void zero_state_kernel(float* p, int n) {
    int i = blockIdx.x * blockDim.x + threadIdx.x;
    int stride = gridDim.x * blockDim.x;
    for (; i < n; i += stride) p[i] = 0.0f;
}

// ---------------------------------------------------------------------------
// fp32 -> bf16 (round-to-nearest-even), vectorized x4
// ---------------------------------------------------------------------------
__global__ __launch_bounds__(256)
void f32_to_bf16_kernel(const float* __restrict__ src,
                        unsigned short* __restrict__ dst, int n4) {
    int i = blockIdx.x * blockDim.x + threadIdx.x;
    int stride = gridDim.x * blockDim.x;
    for (; i < n4; i += stride) {
        float4 v = ((const float4*)src)[i];
        ush4 o;
        o[0] = f2bf_rn(v.x); o[1] = f2bf_rn(v.y);
        o[2] = f2bf_rn(v.z); o[3] = f2bf_rn(v.w);
        ((ush4*)dst)[i] = o;
    }
}

// ---------------------------------------------------------------------------
// fp32 [R][C] -> bf16 transposed [C][R]  (for spk-GEMM B operands)
// ---------------------------------------------------------------------------
__global__ __launch_bounds__(256)
void transpose_bf16_kernel(const float* __restrict__ W,
                           unsigned short* __restrict__ WT, int R, int C) {
    __shared__ float ts[64][65];
    int tid = threadIdx.x;
    int c0 = blockIdx.x * 64;
    int r0 = blockIdx.y * 64;
    #pragma unroll
    for (int rr = 0; rr < 16; ++rr) {
        int r = rr * 4 + (tid >> 6);
        int c = tid & 63;
        ts[r][c] = W[(size_t)(r0 + r) * C + c0 + c];
    }
    __syncthreads();
    #pragma unroll
    for (int rr = 0; rr < 16; ++rr) {
        int c = rr * 4 + (tid >> 6);
        int r = tid & 63;
        WT[(size_t)(c0 + c) * R + r0 + r] = f2bf_rn(ts[r][c]);
    }
}

// ---------------------------------------------------------------------------
// column sums of the bf16-rounded W_rec / W_out (for the sparse complement)
// ---------------------------------------------------------------------------
__global__ __launch_bounds__(256)
void colsum_bf16_kernel(const unsigned short* __restrict__ WrecB,
                        const unsigned short* __restrict__ WoutB,
                        float* __restrict__ cs_rec, float* __restrict__ cs_out) {
    __shared__ float part[4][64];
    int tid = threadIdx.x;
    int c = tid & 63, q = tid >> 6;
    int col = blockIdx.x * 64 + c;  // 0..5119
    float s = 0.f;
    if (col < N_HID) {
        const unsigned short* p = WrecB + col + (size_t)q * 1024 * N_HID;
        for (int j = 0; j < 1024; ++j) s += bf2f(p[(size_t)j * N_HID]);
    } else {
        int o = col - N_HID;
        const unsigned short* p = WoutB + o + (size_t)q * 1024 * N_OUT;
        for (int j = 0; j < 1024; ++j) s += bf2f(p[(size_t)j * N_OUT]);
    }
    part[q][c] = s;
    __syncthreads();
    if (tid < 64) {
        float tot = part[0][tid] + part[1][tid] + part[2][tid] + part[3][tid];
        int col2 = blockIdx.x * 64 + tid;
        if (col2 < N_HID) cs_rec[col2] = tot;
        else              cs_out[col2 - N_HID] = tot;
    }
}

// ---------------------------------------------------------------------------
// x [B,T,1024] fp32 -> Ax [128*Tc][2048] bf16  (cols 0..1023 hi, 1024..2047 lo)
// ---------------------------------------------------------------------------
__global__ __launch_bounds__(256)
void convert_x_kernel(const float* __restrict__ x, unsigned short* __restrict__ Ax,
                      int t0, int Tc) {
    int total4 = B_SZ * Tc * (N_IN / 4);
    int i = blockIdx.x * blockDim.x + threadIdx.x;
    int stride = gridDim.x * blockDim.x;
    for (; i < total4; i += stride) {
        int m = i >> 8;
        int c4 = i & 255;
        int b = m / Tc, tl = m - b * Tc;
        float4 v = *(const float4*)(x + ((size_t)(b * T_SZ + t0 + tl) * N_IN) + c4 * 4);
        ush4 hi, lo;
        float f[4] = {v.x, v.y, v.z, v.w};
        #pragma unroll
        for (int j = 0; j < 4; ++j) {
            unsigned short h = f2bf_rn(f[j]);
            hi[j] = h;
            lo[j] = f2bf_rn(f[j] - bf2f(h));
        }
        unsigned short* row = Ax + (size_t)m * 2048;
        *(ush4*)(row + c4 * 4)        = hi;
        *(ush4*)(row + 1024 + c4 * 4) = lo;
    }
}

// ---------------------------------------------------------------------------
// W_fc1 [1024][4096] fp32 -> Bt [4096][2048] bf16, transposed (hi|lo)
// ---------------------------------------------------------------------------
__global__ __launch_bounds__(256)
void convert_w_kernel(const float* __restrict__ W, unsigned short* __restrict__ Bt) {
    __shared__ float ts[32][65];
    int tid = threadIdx.x;
    int k0 = blockIdx.x * 32;
    int n0 = blockIdx.y * 64;
    #pragma unroll
    for (int rr = 0; rr < 8; ++rr) {
        int kl = (tid >> 6) * 8 + rr;
        int nl = tid & 63;
        ts[kl][nl] = W[(size_t)(k0 + kl) * N_HID + n0 + nl];
    }
    __syncthreads();
    #pragma unroll
    for (int rr = 0; rr < 8; ++rr) {
        int nl = (tid >> 5) + rr * 8;
        int kl = tid & 31;
        float v = ts[kl][nl];
        unsigned short h = f2bf_rn(v);
        unsigned short l = f2bf_rn(v - bf2f(h));
        unsigned short* row = Bt + (size_t)(n0 + nl) * 2048;
        row[k0 + kl]        = h;
        row[1024 + k0 + kl] = l;
    }
}

// ---------------------------------------------------------------------------
// MFMA NT-GEMM for fc1, K'=3072 virtual (bf16x3). Unchanged (m97 structure).
// ---------------------------------------------------------------------------
__global__ __launch_bounds__(256)
void fc1_mfma_kernel(const unsigned short* __restrict__ A,
                     const unsigned short* __restrict__ Bt,
                     float* __restrict__ C) {
    __shared__ __attribute__((aligned(16))) unsigned short As[128 * 32];
    __shared__ __attribute__((aligned(16))) unsigned short Bs[128 * 32];
    const int tid = threadIdx.x;
    const int lane = tid & 63;
    const int wave = tid >> 6;
    const int wm = (wave >> 1) * 64;
    const int wn = (wave & 1) * 64;
    const int quad = lane >> 4, l16 = lane & 15;
    const int m0 = blockIdx.y * 128, n0 = blockIdx.x * 128;

    const unsigned short* aptr[2];
    const unsigned short* bptr[2];
    unsigned short* alds[2];
    unsigned short* blds[2];
    #pragma unroll
    for (int i = 0; i < 2; ++i) {
        int idx = tid + 256 * i;
        int row = idx >> 2, cg = idx & 3;
        aptr[i] = A  + (size_t)(m0 + row) * 2048 + cg * 8;
        bptr[i] = Bt + (size_t)(n0 + row) * 2048 + cg * 8;
        alds[i] = As + idx * 8;
        blds[i] = Bs + idx * 8;
    }

    f32x4 acc[4][4] = {};
    for (int kt = 0; kt < 96; ++kt) {
        int kk = kt * 32;
        int ak = (kk < 2048) ? kk : kk - 2048;
        int bk = (kk < 1024) ? kk : kk - 1024;
        __syncthreads();
        #pragma unroll
        for (int i = 0; i < 2; ++i) {
            gload_lds16(aptr[i] + ak, alds[i]);
            gload_lds16(bptr[i] + bk, blds[i]);
        }
        __syncthreads();
        sh8 af[4], bf[4];
        #pragma unroll
        for (int mt = 0; mt < 4; ++mt)
            af[mt] = *(const sh8*)&As[(wm + mt * 16 + l16) * 32 + quad * 8];
        #pragma unroll
        for (int nt = 0; nt < 4; ++nt)
            bf[nt] = *(const sh8*)&Bs[(wn + nt * 16 + l16) * 32 + quad * 8];
        #pragma unroll
        for (int mt = 0; mt < 4; ++mt)
            #pragma unroll
            for (int nt = 0; nt < 4; ++nt)
                acc[mt][nt] = __builtin_amdgcn_mfma_f32_16x16x32_bf16(
                    af[mt], bf[nt], acc[mt][nt], 0, 0, 0);
    }
    #pragma unroll
    for (int mt = 0; mt < 4; ++mt)
        #pragma unroll
        for (int nt = 0; nt < 4; ++nt) {
            int col = n0 + wn + nt * 16 + l16;
            #pragma unroll
            for (int r = 0; r < 4; ++r) {
                int m = m0 + wm + mt * 16 + quad * 4 + r;
                C[(size_t)m * N_HID + col] = acc[mt][nt][r];
            }
        }
}

// ---------------------------------------------------------------------------
// One 128x128 C-tile of part[ks][128][Nfull] = spk[128][4096] @ BT[...]^T over
// a 512-wide K chunk. Bit-identical to round-6's spk_gemm_kernel tile.
// ---------------------------------------------------------------------------
__device__ __forceinline__ void spk_tile_gemm(const unsigned short* __restrict__ A,
                                              const unsigned short* __restrict__ BT,
                                              float* __restrict__ part, int Nfull,
                                              int nt, int ks,
                                              unsigned short* As, unsigned short* Bs,
                                              int tid) {
    const int lane = tid & 63;
    const int wave = tid >> 6;
    const int wm = (wave >> 1) * 64;
    const int wn = (wave & 1) * 64;
    const int quad = lane >> 4, l16 = lane & 15;
    const int n0 = nt * 128;
    const int k0 = ks * (N_HID / KSPLIT);

    const unsigned short* aptr[2];
    const unsigned short* bptr[2];
    unsigned short* alds[2];
    unsigned short* blds[2];
    #pragma unroll
    for (int i = 0; i < 2; ++i) {
        int idx = tid + 256 * i;
        int row = idx >> 2, cg = idx & 3;
        aptr[i] = A  + (size_t)row * N_HID + k0 + cg * 8;
        bptr[i] = BT + (size_t)(n0 + row) * N_HID + k0 + cg * 8;
        alds[i] = As + idx * 8;
        blds[i] = Bs + idx * 8;
    }

    f32x4 acc[4][4] = {};
    for (int kt = 0; kt < (N_HID / KSPLIT) / 32; ++kt) {   // 16 iters
        int kk = kt * 32;
        __syncthreads();
        #pragma unroll
        for (int i = 0; i < 2; ++i) {
            gload_lds16(aptr[i] + kk, alds[i]);
            gload_lds16(bptr[i] + kk, blds[i]);
        }
        __syncthreads();
        sh8 af[4], bf[4];
        #pragma unroll
        for (int mt = 0; mt < 4; ++mt)
            af[mt] = *(const sh8*)&As[(wm + mt * 16 + l16) * 32 + quad * 8];
        #pragma unroll
        for (int nt2 = 0; nt2 < 4; ++nt2)
            bf[nt2] = *(const sh8*)&Bs[(wn + nt2 * 16 + l16) * 32 + quad * 8];
        #pragma unroll
        for (int mt = 0; mt < 4; ++mt)
            #pragma unroll
            for (int nt2 = 0; nt2 < 4; ++nt2)
                acc[mt][nt2] = __builtin_amdgcn_mfma_f32_16x16x32_bf16(
                    af[mt], bf[nt2], acc[mt][nt2], 0, 0, 0);
    }
    float* pout = part + (size_t)ks * 128 * Nfull;
    #pragma unroll
    for (int mt = 0; mt < 4; ++mt)
        #pragma unroll
        for (int nt2 = 0; nt2 < 4; ++nt2) {
            int col = n0 + wn + nt2 * 16 + l16;
            #pragma unroll
            for (int r = 0; r < 4; ++r) {
                int m = wm + mt * 16 + quad * 4 + r;
                pout[(size_t)m * Nfull + col] = acc[mt][nt2][r];
            }
        }
}

// ---------------------------------------------------------------------------
// Cooperative dense transient: 256 blocks x 256 threads, all co-resident.
// Per step: phase U (blocks 0..127 = one batch each: LIF pointwise + spike
// write) -> grid.sync -> phase G (every block one rec C-tile [32nt x 8ks];
// every 4th block additionally one out C-tile [8nt x 8ks]) -> grid.sync.
// Arithmetic is element/tile-wise identical to round-6's separate kernels.
// ---------------------------------------------------------------------------
__global__ __launch_bounds__(256, 2)
void transient_coop_kernel(const float* __restrict__ inp,      // [B][Tc][N_HID]
                           const unsigned short* __restrict__ WrecT,
                           const unsigned short* __restrict__ WoutT,
                           float* __restrict__ rec_part,       // [KSPLIT][B][N_HID]
                           float* __restrict__ out_part,       // [KSPLIT][B][N_OUT]
                           float* __restrict__ h_mem,
                           float* __restrict__ o_mem,
                           unsigned short* __restrict__ spk,   // [B][N_HID] bf16
                           unsigned long long* __restrict__ maskg,
                           float* __restrict__ out,
                           int Tc) {
    __shared__ __attribute__((aligned(16))) unsigned short As[128 * 32];
    __shared__ __attribute__((aligned(16))) unsigned short Bs[128 * 32];
    __shared__ __attribute__((aligned(16))) unsigned char spkb[1024];
    cg::grid_group grid = cg::this_grid();

    const int bid = blockIdx.x;      // 0..255
    const int tid = threadIdx.x;     // 0..255
    const int lane = tid & 63;
    const int wave = tid >> 6;

    for (int tg = 0; tg < S_DENSE; ++tg) {
        // ---------------- phase U: pointwise LIF update ----------------
        if (bid < B_SZ) {
            const int b = bid;
            if (tg > 0) {
                #pragma unroll
                for (int j = 0; j < 4; ++j) {
                    int col = tid + 256 * j;
                    float s = 0.f;
                    #pragma unroll
                    for (int ks = 0; ks < KSPLIT; ++ks)
                        s += out_part[(size_t)ks * B_SZ * N_OUT + (size_t)b * N_OUT + col];
                    float o = TAU * o_mem[(size_t)b * N_OUT + col] + s;
                    o_mem[(size_t)b * N_OUT + col] = o;
                    out[((size_t)b * T_SZ + (tg - 1)) * N_OUT + col] = o;
                }
            }
            #pragma unroll
            for (int j = 0; j < 4; ++j) {
                int t4 = tid + 256 * j;          // owns h cols 4*t4..4*t4+3
                float rec[4] = {0.f, 0.f, 0.f, 0.f};
                if (tg > 0) {
                    #pragma unroll
                    for (int ks = 0; ks < KSPLIT; ++ks) {
                        float4 p = *(const float4*)(rec_part + (size_t)ks * B_SZ * N_HID
                                                    + (size_t)b * N_HID + 4 * t4);
                        rec[0] += p.x; rec[1] += p.y; rec[2] += p.z; rec[3] += p.w;
                    }
                }
                unsigned short* sp = spk + (size_t)b * N_HID + 4 * t4;
                ush4 prev = *(const ush4*)sp;    // bf16 {0,1}; tg=0: h=0 so unused
                float4 iv = *(const float4*)(inp + ((size_t)b * Tc + tg) * N_HID + 4 * t4);
                float ivv[4] = {iv.x, iv.y, iv.z, iv.w};
                float* hp = h_mem + (size_t)b * N_HID + 4 * t4;
                float hv[4] = {hp[0], hp[1], hp[2], hp[3]};
                ush4 news;
                unsigned nib = 0;
                #pragma unroll
                for (int k = 0; k < 4; ++k) {
                    float spf = bf2f(prev[k]);
                    float v = TAU * hv[k] * (1.0f - spf) + (ivv[k] + REC_SCALE * rec[k]);
                    hp[k] = v;
                    bool s = (v >= THRESH);
                    news[k] = s ? (unsigned short)0x3F80 : (unsigned short)0;
                    nib |= (s ? 1u : 0u) << k;
                }
                *(ush4*)sp = news;
                spkb[t4] = (unsigned char)nib;
            }
            __syncthreads();
            if (wave == 0) {
                uint4 q = *(const uint4*)&spkb[lane * 16];
                unsigned w0 = pack4(q.x) | (pack4(q.y) << 16);
                unsigned w1 = pack4(q.z) | (pack4(q.w) << 16);
                maskg[b * 64 + lane] = (unsigned long long)w0
                                     | ((unsigned long long)w1 << 32);
            }
        }
        grid.sync();
        // ---------------- phase G: spk GEMMs for this step's spikes ------
        if (tg + 1 < S_DENSE) {
            // rec partials for the NEXT step: 32 n-tiles x 8 ksplit = 256 blocks
            spk_tile_gemm(spk, WrecT, rec_part, N_HID,
                          bid & 31, bid >> 5, As, Bs, tid);
        }
        if ((bid & 3) == 0) {
            // out partials for THIS step: 8 n-tiles x 8 ksplit = 64 tiles
            int o = bid >> 2;
            spk_tile_gemm(spk, WoutT, out_part, N_OUT,
                          o & 7, o >> 3, As, Bs, tid);
        }
        grid.sync();
    }
}

// ---------------------------------------------------------------------------
// min-side list build from a 64-bit word per lane (wave 0 only).
// ---------------------------------------------------------------------------
__device__ __forceinline__ void build_list_core(unsigned long long w,
                                                unsigned short* list,
                                                int* sh_n, int* sh_inact,
                                                int lane) {
    int tot = __builtin_popcountll(w);
    #pragma unroll
    for (int d = 32; d > 0; d >>= 1) tot += __shfl_xor(tot, d, 64);
    int inact = tot > (N_HID / 2);
    unsigned long long wsel = inact ? ~w : w;
    int c = __builtin_popcountll(wsel);
    int scan = c;
    #pragma unroll
    for (int d = 1; d < 64; d <<= 1) {
        int v = __shfl_up(scan, d, 64);
        if (lane >= d) scan += v;
    }
    int off = scan - c;
    while (wsel) {
        int bpos = __builtin_ctzll(wsel);
        list[off++] = (unsigned short)(lane * 64 + bpos);
        wsel &= wsel - 1;
    }
    if (lane == 0) {
        *sh_n = inact ? (N_HID - tot) : tot;
        *sh_inact = inact;
    }
}

// ---------------------------------------------------------------------------
// Sparse RSNN step loop for steps tloc0..tloc0+nsteps-1 of the current chunk.
// ---------------------------------------------------------------------------
__global__ __launch_bounds__(1024, 4)
void rsnn_step_kernel(const float* __restrict__ inp,            // [B][Tc][N_HID]
                      const unsigned short* __restrict__ WrecB, // [N_HID][N_HID] bf16
                      const unsigned short* __restrict__ WoutB, // [N_HID][N_OUT] bf16
                      const float* __restrict__ cs_rec,
                      const float* __restrict__ cs_out,
                      const float* __restrict__ out_part,       // [KSPLIT][B][N_OUT]
                      float* __restrict__ h_mem_g,
                      float* __restrict__ o_mem_g,
                      unsigned long long* __restrict__ mask_g,
                      float* __restrict__ out,
                      int t0, int Tc, int tloc0, int nsteps, int do_accum) {
    __shared__ unsigned long long mask[64];
    __shared__ __attribute__((aligned(16))) unsigned short list[N_HID];
    __shared__ __attribute__((aligned(16))) unsigned char spk[1024];
    __shared__ int sh_n;
    __shared__ int sh_inact;

    const int b = blockIdx.x;
    const int t = threadIdx.x;           // 0..1023
    const int lane = t & 63;
    const int wave = t >> 6;

    float hm[4], csr[4];
    #pragma unroll
    for (int k = 0; k < 4; ++k) {
        hm[k]  = h_mem_g[(size_t)b * N_HID + 4 * t + k];
        csr[k] = cs_rec[4 * t + k];
    }
    float om  = o_mem_g[(size_t)b * N_OUT + t];
    float cso = cs_out[t];
    if (do_accum) {
        float s = 0.f;
        #pragma unroll
        for (int ks = 0; ks < KSPLIT; ++ks)
            s += out_part[(size_t)ks * B_SZ * N_OUT + (size_t)b * N_OUT + t];
        om = TAU * om + s;
        out[((size_t)b * T_SZ + (t0 + tloc0 - 1)) * N_OUT + t] = om;
    }
    if (t < 64) mask[t] = mask_g[b * 64 + t];
    __syncthreads();

    // previous-step spike flags for cols 4t..4t+3 (hard reset term)
    float spf[4];
    {
        unsigned long long w = mask[t >> 4];
        int sh = 4 * (t & 15);
        #pragma unroll
        for (int k = 0; k < 4; ++k)
            spf[k] = (float)((w >> (sh + k)) & 1ULL);
    }
    if (wave == 0) build_list_core(mask[lane], list, &sh_n, &sh_inact, lane);
    __syncthreads();

    const unsigned short* Wb = WrecB + 4 * t;
    const unsigned short* Wo = WoutB + t;

    for (int tl = 0; tl < nsteps; ++tl) {
        // ---- recurrent gather over min side of previous spikes ----
        int n = sh_n, inact = sh_inact;
        float a[8][4] = {};
        int i = 0;
        for (; i + 8 <= n; i += 8) {
            ush8 jv = *(const ush8*)&list[i];
            #pragma unroll
            for (int r = 0; r < 8; ++r) {
                uint2 v = *(const uint2*)(Wb + (size_t)jv[r] * N_HID);
                a[r][0] += __uint_as_float(v.x << 16);
                a[r][1] += __uint_as_float(v.x & 0xFFFF0000u);
                a[r][2] += __uint_as_float(v.y << 16);
                a[r][3] += __uint_as_float(v.y & 0xFFFF0000u);
            }
        }
        for (; i < n; ++i) {
            uint2 v = *(const uint2*)(Wb + (size_t)list[i] * N_HID);
            a[0][0] += __uint_as_float(v.x << 16);
            a[0][1] += __uint_as_float(v.x & 0xFFFF0000u);
            a[0][2] += __uint_as_float(v.y << 16);
            a[0][3] += __uint_as_float(v.y & 0xFFFF0000u);
        }
        float racc[4];
        #pragma unroll
        for (int k = 0; k < 4; ++k)
            racc[k] = ((a[0][k] + a[1][k]) + (a[2][k] + a[3][k]))
                    + ((a[4][k] + a[5][k]) + (a[6][k] + a[7][k]));

        float4 iv = *(const float4*)(inp + ((size_t)b * Tc + tloc0 + tl) * N_HID + 4 * t);
        float ivv[4] = {iv.x, iv.y, iv.z, iv.w};
        unsigned nib = 0;
        #pragma unroll
        for (int k = 0; k < 4; ++k) {
            float rec = REC_SCALE * (inact ? (csr[k] - racc[k]) : racc[k]);
            float v = TAU * hm[k] * (1.0f - spf[k]) + (ivv[k] + rec);
            hm[k] = v;
            bool s = (v >= THRESH);
            spf[k] = s ? 1.0f : 0.0f;
            nib |= (s ? 1u : 0u) << k;
        }
        __syncthreads();            // all list readers done before overwrite
        spk[t] = (unsigned char)nib;
        __syncthreads();            // spk visible to wave 0
        if (wave == 0) {
            uint4 q = *(const uint4*)&spk[lane * 16];
            unsigned w0 = pack4(q.x) | (pack4(q.y) << 16);
            unsigned w1 = pack4(q.z) | (pack4(q.w) << 16);
            unsigned long long w = (unsigned long long)w0
                                 | ((unsigned long long)w1 << 32);
            mask[lane] = w;
            build_list_core(w, list, &sh_n, &sh_inact, lane);
        }
        __syncthreads();            // list/counts ready

        // ---- output gather over min side of NEW spikes ----
        int n2 = sh_n; inact = sh_inact;
        float o8[8] = {};
        i = 0;
        for (; i + 16 <= n2; i += 16) {
            ush8 j0 = *(const ush8*)&list[i];
            ush8 j1 = *(const ush8*)&list[i + 8];
            #pragma unroll
            for (int r = 0; r < 8; ++r) o8[r] += bf2f(Wo[(size_t)j0[r] * N_OUT]);
            #pragma unroll
            for (int r = 0; r < 8; ++r) o8[r] += bf2f(Wo[(size_t)j1[r] * N_OUT]);
        }
        for (; i + 8 <= n2; i += 8) {
            ush8 j0 = *(const ush8*)&list[i];
            #pragma unroll
            for (int r = 0; r < 8; ++r) o8[r] += bf2f(Wo[(size_t)j0[r] * N_OUT]);
        }
        for (; i < n2; ++i) o8[0] += bf2f(Wo[(size_t)list[i] * N_OUT]);
        float oacc = ((o8[0] + o8[1]) + (o8[2] + o8[3]))
                   + ((o8[4] + o8[5]) + (o8[6] + o8[7]));
        float contrib = inact ? (cso - oacc) : oacc;
        om = TAU * om + contrib;
        out[((size_t)b * T_SZ + (t0 + tloc0 + tl)) * N_OUT + t] = om;
    }

    #pragma unroll
    for (int k = 0; k < 4; ++k)
        h_mem_g[(size_t)b * N_HID + 4 * t + k] = hm[k];
    o_mem_g[(size_t)b * N_OUT + t] = om;
    __syncthreads();
    if (t < 64) mask_g[b * 64 + t] = mask[t];
}

// ---------------------------------------------------------------------------
extern "C" void kernel_launch(void* const* d_in, const int* in_sizes, int n_in,
                              void* d_out, int out_size, void* d_ws, size_t ws_size,
                              hipStream_t stream) {
    const float* x    = (const float*)d_in[0];
    const float* Wfc1 = (const float*)d_in[1];
    const float* Wrec = (const float*)d_in[2];
    const float* Wout = (const float*)d_in[3];
    float* out = (float*)d_out;

    // workspace layout (all 16B-aligned)
    float* h_mem = (float*)d_ws;                               // 2 MB
    float* o_mem = h_mem + B_SZ * N_HID;                       // 0.5 MB
    unsigned long long* maskg =
        (unsigned long long*)(o_mem + B_SZ * N_OUT);           // 64 KB
    float* cs_rec = (float*)(maskg + B_SZ * 64);               // 16 KB
    float* cs_out = cs_rec + N_HID;                            // 4 KB
    unsigned short* WrecB = (unsigned short*)(cs_out + N_OUT); // 33.55 MB
    unsigned short* WoutB = WrecB + (size_t)N_HID * N_HID;     // 8.39 MB
    unsigned short* WrecT = WoutB + (size_t)N_HID * N_OUT;     // 33.55 MB
    unsigned short* WoutT = WrecT + (size_t)N_HID * N_HID;     // 8.39 MB
    unsigned short* Bt    = WoutT + (size_t)N_OUT * N_HID;     // 16.78 MB
    unsigned short* spk   = Bt + (size_t)N_HID * 2048;         // 1.05 MB
    float* rec_part = (float*)(spk + (size_t)B_SZ * N_HID);    // 16.78 MB
    float* out_part = rec_part + (size_t)KSPLIT * B_SZ * N_HID;// 4.19 MB
    unsigned short* Ax = (unsigned short*)(out_part + (size_t)KSPLIT * B_SZ * N_OUT);
    // inp_chunk follows Ax (Tc-dependent)

    size_t fixed_bytes = (size_t)(B_SZ * N_HID + B_SZ * N_OUT) * 4
                       + (size_t)B_SZ * 64 * 8
                       + (size_t)(N_HID + N_OUT) * 4
                       + 2 * (size_t)N_HID * N_HID * 2          // WrecB + WrecT
                       + 2 * (size_t)N_HID * N_OUT * 2          // WoutB + WoutT
                       + (size_t)N_HID * 2048 * 2               // Bt
                       + (size_t)B_SZ * N_HID * 2               // spk
                       + (size_t)KSPLIT * B_SZ * (N_HID + N_OUT) * 4;
    int Tc = 64;
    while (Tc > 8 &&
           fixed_bytes + (size_t)Tc * (B_SZ * 2048 * 2 + B_SZ * N_HID * 4) > ws_size)
        Tc >>= 1;
    float* inp_chunk = (float*)(Ax + (size_t)B_SZ * Tc * 2048);

    int state_floats = B_SZ * N_HID + B_SZ * N_OUT + B_SZ * 64 * 2;
    zero_state_kernel<<<256, 256, 0, stream>>>(h_mem, state_floats);
    f32_to_bf16_kernel<<<2048, 256, 0, stream>>>(Wrec, WrecB, N_HID * N_HID / 4);
    f32_to_bf16_kernel<<<1024, 256, 0, stream>>>(Wout, WoutB, N_HID * N_OUT / 4);
    transpose_bf16_kernel<<<dim3(N_HID / 64, N_HID / 64), 256, 0, stream>>>(
        Wrec, WrecT, N_HID, N_HID);
    transpose_bf16_kernel<<<dim3(N_OUT / 64, N_HID / 64), 256, 0, stream>>>(
        Wout, WoutT, N_HID, N_OUT);
    colsum_bf16_kernel<<<80, 256, 0, stream>>>(WrecB, WoutB, cs_rec, cs_out);
    convert_w_kernel<<<dim3(32, 64), 256, 0, stream>>>(Wfc1, Bt);

    for (int t0 = 0; t0 < T_SZ; t0 += Tc) {
        convert_x_kernel<<<2048, 256, 0, stream>>>(x, Ax, t0, Tc);
        fc1_mfma_kernel<<<dim3(N_HID / 128, Tc), 256, 0, stream>>>(Ax, Bt, inp_chunk);

        if (t0 == 0) {
            // dense transient: steps 0..S_DENSE-1 in ONE cooperative kernel
            void* args[] = {(void*)&inp_chunk, (void*)&WrecT, (void*)&WoutT,
                            (void*)&rec_part, (void*)&out_part,
                            (void*)&h_mem, (void*)&o_mem, (void*)&spk,
                            (void*)&maskg, (void*)&out, (void*)&Tc};
            hipLaunchCooperativeKernel(
                reinterpret_cast<void*>(transient_coop_kernel),
                dim3(256), dim3(256), args, 0, stream);
            rsnn_step_kernel<<<B_SZ, 1024, 0, stream>>>(
                inp_chunk, WrecB, WoutB, cs_rec, cs_out, out_part,
                h_mem, o_mem, maskg, out,
                t0, Tc, /*tloc0=*/S_DENSE, /*nsteps=*/Tc - S_DENSE, /*do_accum=*/1);
        } else {
            rsnn_step_kernel<<<B_SZ, 1024, 0, stream>>>(
                inp_chunk, WrecB, WoutB, cs_rec, cs_out, out_part,
                h_mem, o_mem, maskg, out,
                t0, Tc, /*tloc0=*/0, /*nsteps=*/Tc, /*do_accum=*/0);
        }
    }
}

// Round 8
// 727.390 us; speedup vs baseline: 2.0384x; 2.0384x over previous
//
#include <hip/hip_runtime.h>
#include <stdint.h>

#define B_SZ 128
#define T_SZ 64
#define N_IN 1024
#define N_HID 4096
#define N_OUT 1024
#define TAU 0.9f
#define THRESH 0.5f
#define REC_SCALE 0.1f
#define S_DENSE 5          // steps 0..4 computed via dense MFMA GEMMs
#define KSPLIT 8           // K-split for spk GEMMs (4096/8 = 512 per chunk)

typedef __attribute__((ext_vector_type(8))) short sh8;
typedef __attribute__((ext_vector_type(4))) float f32x4;
typedef __attribute__((ext_vector_type(4))) unsigned short ush4;
typedef __attribute__((ext_vector_type(8))) unsigned short ush8;

// ---------------------------------------------------------------------------
// helpers
// ---------------------------------------------------------------------------
__device__ __forceinline__ unsigned short f2bf_rn(float f) {
    unsigned u = __float_as_uint(f);
    unsigned r = (u + 0x7FFFu + ((u >> 16) & 1u)) >> 16;
    return (unsigned short)r;
}
__device__ __forceinline__ float bf2f(unsigned short h) {
    return __uint_as_float((unsigned)h << 16);
}
__device__ __forceinline__ void gload_lds16(const void* g, void* l) {
    __builtin_amdgcn_global_load_lds(
        (const __attribute__((address_space(1))) void*)g,
        (__attribute__((address_space(3))) void*)l, 16, 0, 0);
}
// compress low nibbles of 4 bytes into 16 bits
__device__ __forceinline__ unsigned pack4(unsigned a) {
    a &= 0x0F0F0F0Fu;
    a = (a | (a >> 4)) & 0x00FF00FFu;
    a = (a | (a >> 8)) & 0x0000FFFFu;
    return a;
}

// ---------------------------------------------------------------------------
__global__ void zero_state_kernel(float* p, int n) {
    int i = blockIdx.x * blockDim.x + threadIdx.x;
    int stride = gridDim.x * blockDim.x;
    for (; i < n; i += stride) p[i] = 0.0f;
}

// ---------------------------------------------------------------------------
// fused: W [R][C] fp32 -> WB [R][C] bf16 AND WT [C][R] bf16 (one read of W)
// ---------------------------------------------------------------------------
__global__ __launch_bounds__(256)
void convT_bf16_kernel(const float* __restrict__ W,
                       unsigned short* __restrict__ WB,
                       unsigned short* __restrict__ WT, int R, int C) {
    __shared__ float ts[64][65];
    int tid = threadIdx.x;
    int c0 = blockIdx.x * 64;
    int r0 = blockIdx.y * 64;
    #pragma unroll
    for (int rr = 0; rr < 16; ++rr) {
        int r = rr * 4 + (tid >> 6);
        int c = tid & 63;
        float v = W[(size_t)(r0 + r) * C + c0 + c];
        ts[r][c] = v;
        WB[(size_t)(r0 + r) * C + c0 + c] = f2bf_rn(v);
    }
    __syncthreads();
    #pragma unroll
    for (int rr = 0; rr < 16; ++rr) {
        int c = rr * 4 + (tid >> 6);
        int r = tid & 63;
        WT[(size_t)(c0 + c) * R + r0 + r] = f2bf_rn(ts[r][c]);
    }
}

// ---------------------------------------------------------------------------
// column sums of the bf16-rounded W_rec / W_out (for the sparse complement)
// ---------------------------------------------------------------------------
__global__ __launch_bounds__(256)
void colsum_bf16_kernel(const unsigned short* __restrict__ WrecB,
                        const unsigned short* __restrict__ WoutB,
                        float* __restrict__ cs_rec, float* __restrict__ cs_out) {
    __shared__ float part[4][64];
    int tid = threadIdx.x;
    int c = tid & 63, q = tid >> 6;
    int col = blockIdx.x * 64 + c;  // 0..5119
    float s = 0.f;
    if (col < N_HID) {
        const unsigned short* p = WrecB + col + (size_t)q * 1024 * N_HID;
        for (int j = 0; j < 1024; ++j) s += bf2f(p[(size_t)j * N_HID]);
    } else {
        int o = col - N_HID;
        const unsigned short* p = WoutB + o + (size_t)q * 1024 * N_OUT;
        for (int j = 0; j < 1024; ++j) s += bf2f(p[(size_t)j * N_OUT]);
    }
    part[q][c] = s;
    __syncthreads();
    if (tid < 64) {
        float tot = part[0][tid] + part[1][tid] + part[2][tid] + part[3][tid];
        int col2 = blockIdx.x * 64 + tid;
        if (col2 < N_HID) cs_rec[col2] = tot;
        else              cs_out[col2 - N_HID] = tot;
    }
}

// ---------------------------------------------------------------------------
// x [B,T,1024] fp32 -> Ax [128*Tc][2048] bf16  (cols 0..1023 hi, 1024..2047 lo)
// ---------------------------------------------------------------------------
__global__ __launch_bounds__(256)
void convert_x_kernel(const float* __restrict__ x, unsigned short* __restrict__ Ax,
                      int t0, int Tc) {
    int total4 = B_SZ * Tc * (N_IN / 4);
    int i = blockIdx.x * blockDim.x + threadIdx.x;
    int stride = gridDim.x * blockDim.x;
    for (; i < total4; i += stride) {
        int m = i >> 8;
        int c4 = i & 255;
        int b = m / Tc, tl = m - b * Tc;
        float4 v = *(const float4*)(x + ((size_t)(b * T_SZ + t0 + tl) * N_IN) + c4 * 4);
        ush4 hi, lo;
        float f[4] = {v.x, v.y, v.z, v.w};
        #pragma unroll
        for (int j = 0; j < 4; ++j) {
            unsigned short h = f2bf_rn(f[j]);
            hi[j] = h;
            lo[j] = f2bf_rn(f[j] - bf2f(h));
        }
        unsigned short* row = Ax + (size_t)m * 2048;
        *(ush4*)(row + c4 * 4)        = hi;
        *(ush4*)(row + 1024 + c4 * 4) = lo;
    }
}

// ---------------------------------------------------------------------------
// W_fc1 [1024][4096] fp32 -> Bt [4096][2048] bf16, transposed (hi|lo)
// ---------------------------------------------------------------------------
__global__ __launch_bounds__(256)
void convert_w_kernel(const float* __restrict__ W, unsigned short* __restrict__ Bt) {
    __shared__ float ts[32][65];
    int tid = threadIdx.x;
    int k0 = blockIdx.x * 32;
    int n0 = blockIdx.y * 64;
    #pragma unroll
    for (int rr = 0; rr < 8; ++rr) {
        int kl = (tid >> 6) * 8 + rr;
        int nl = tid & 63;
        ts[kl][nl] = W[(size_t)(k0 + kl) * N_HID + n0 + nl];
    }
    __syncthreads();
    #pragma unroll
    for (int rr = 0; rr < 8; ++rr) {
        int nl = (tid >> 5) + rr * 8;
        int kl = tid & 31;
        float v = ts[kl][nl];
        unsigned short h = f2bf_rn(v);
        unsigned short l = f2bf_rn(v - bf2f(h));
        unsigned short* row = Bt + (size_t)(n0 + nl) * 2048;
        row[k0 + kl]        = h;
        row[1024 + k0 + kl] = l;
    }
}

// ---------------------------------------------------------------------------
// MFMA NT-GEMM for fc1, K'=3072 virtual (bf16x3). Unchanged (m97 structure).
// ---------------------------------------------------------------------------
__global__ __launch_bounds__(256)
void fc1_mfma_kernel(const unsigned short* __restrict__ A,
                     const unsigned short* __restrict__ Bt,
                     float* __restrict__ C) {
    __shared__ __attribute__((aligned(16))) unsigned short As[128 * 32];
    __shared__ __attribute__((aligned(16))) unsigned short Bs[128 * 32];
    const int tid = threadIdx.x;
    const int lane = tid & 63;
    const int wave = tid >> 6;
    const int wm = (wave >> 1) * 64;
    const int wn = (wave & 1) * 64;
    const int quad = lane >> 4, l16 = lane & 15;
    const int m0 = blockIdx.y * 128, n0 = blockIdx.x * 128;

    const unsigned short* aptr[2];
    const unsigned short* bptr[2];
    unsigned short* alds[2];
    unsigned short* blds[2];
    #pragma unroll
    for (int i = 0; i < 2; ++i) {
        int idx = tid + 256 * i;
        int row = idx >> 2, cg = idx & 3;
        aptr[i] = A  + (size_t)(m0 + row) * 2048 + cg * 8;
        bptr[i] = Bt + (size_t)(n0 + row) * 2048 + cg * 8;
        alds[i] = As + idx * 8;
        blds[i] = Bs + idx * 8;
    }

    f32x4 acc[4][4] = {};
    for (int kt = 0; kt < 96; ++kt) {
        int kk = kt * 32;
        int ak = (kk < 2048) ? kk : kk - 2048;
        int bk = (kk < 1024) ? kk : kk - 1024;
        __syncthreads();
        #pragma unroll
        for (int i = 0; i < 2; ++i) {
            gload_lds16(aptr[i] + ak, alds[i]);
            gload_lds16(bptr[i] + bk, blds[i]);
        }
        __syncthreads();
        sh8 af[4], bf[4];
        #pragma unroll
        for (int mt = 0; mt < 4; ++mt)
            af[mt] = *(const sh8*)&As[(wm + mt * 16 + l16) * 32 + quad * 8];
        #pragma unroll
        for (int nt = 0; nt < 4; ++nt)
            bf[nt] = *(const sh8*)&Bs[(wn + nt * 16 + l16) * 32 + quad * 8];
        #pragma unroll
        for (int mt = 0; mt < 4; ++mt)
            #pragma unroll
            for (int nt = 0; nt < 4; ++nt)
                acc[mt][nt] = __builtin_amdgcn_mfma_f32_16x16x32_bf16(
                    af[mt], bf[nt], acc[mt][nt], 0, 0, 0);
    }
    #pragma unroll
    for (int mt = 0; mt < 4; ++mt)
        #pragma unroll
        for (int nt = 0; nt < 4; ++nt) {
            int col = n0 + wn + nt * 16 + l16;
            #pragma unroll
            for (int r = 0; r < 4; ++r) {
                int m = m0 + wm + mt * 16 + quad * 4 + r;
                C[(size_t)m * N_HID + col] = acc[mt][nt][r];
            }
        }
}

// ---------------------------------------------------------------------------
// One 128x128 C-tile of part[ks][128][Nfull] = spk[128][4096] @ BT[...]^T over
// a 512-wide K chunk. Bit-identical to round-6's spk_gemm_kernel tile.
// ---------------------------------------------------------------------------
__device__ __forceinline__ void spk_tile_gemm(const unsigned short* __restrict__ A,
                                              const unsigned short* __restrict__ BT,
                                              float* __restrict__ part, int Nfull,
                                              int nt, int ks,
                                              unsigned short* As, unsigned short* Bs,
                                              int tid) {
    const int lane = tid & 63;
    const int wave = tid >> 6;
    const int wm = (wave >> 1) * 64;
    const int wn = (wave & 1) * 64;
    const int quad = lane >> 4, l16 = lane & 15;
    const int n0 = nt * 128;
    const int k0 = ks * (N_HID / KSPLIT);

    const unsigned short* aptr[2];
    const unsigned short* bptr[2];
    unsigned short* alds[2];
    unsigned short* blds[2];
    #pragma unroll
    for (int i = 0; i < 2; ++i) {
        int idx = tid + 256 * i;
        int row = idx >> 2, cg = idx & 3;
        aptr[i] = A  + (size_t)row * N_HID + k0 + cg * 8;
        bptr[i] = BT + (size_t)(n0 + row) * N_HID + k0 + cg * 8;
        alds[i] = As + idx * 8;
        blds[i] = Bs + idx * 8;
    }

    f32x4 acc[4][4] = {};
    for (int kt = 0; kt < (N_HID / KSPLIT) / 32; ++kt) {   // 16 iters
        int kk = kt * 32;
        __syncthreads();
        #pragma unroll
        for (int i = 0; i < 2; ++i) {
            gload_lds16(aptr[i] + kk, alds[i]);
            gload_lds16(bptr[i] + kk, blds[i]);
        }
        __syncthreads();
        sh8 af[4], bf[4];
        #pragma unroll
        for (int mt = 0; mt < 4; ++mt)
            af[mt] = *(const sh8*)&As[(wm + mt * 16 + l16) * 32 + quad * 8];
        #pragma unroll
        for (int nt2 = 0; nt2 < 4; ++nt2)
            bf[nt2] = *(const sh8*)&Bs[(wn + nt2 * 16 + l16) * 32 + quad * 8];
        #pragma unroll
        for (int mt = 0; mt < 4; ++mt)
            #pragma unroll
            for (int nt2 = 0; nt2 < 4; ++nt2)
                acc[mt][nt2] = __builtin_amdgcn_mfma_f32_16x16x32_bf16(
                    af[mt], bf[nt2], acc[mt][nt2], 0, 0, 0);
    }
    float* pout = part + (size_t)ks * 128 * Nfull;
    #pragma unroll
    for (int mt = 0; mt < 4; ++mt)
        #pragma unroll
        for (int nt2 = 0; nt2 < 4; ++nt2) {
            int col = n0 + wn + nt2 * 16 + l16;
            #pragma unroll
            for (int r = 0; r < 4; ++r) {
                int m = wm + mt * 16 + quad * 4 + r;
                pout[(size_t)m * Nfull + col] = acc[mt][nt2][r];
            }
        }
}

// ---------------------------------------------------------------------------
// Merged per-step spk GEMMs: one dispatch computes BOTH the rec partials
// (blocks 0..255: 32 n-tiles x 8 ksplit) and the out partials (blocks
// 256..319: 8 n-tiles x 8 ksplit). When do_rec==0 (last dense step), grid=64
// and all blocks do out tiles. No grid-wide sync anywhere (round-7 lesson).
// ---------------------------------------------------------------------------
__global__ __launch_bounds__(256)
void spk_gemm_merged_kernel(const unsigned short* __restrict__ spk,
                            const unsigned short* __restrict__ WrecT,
                            const unsigned short* __restrict__ WoutT,
                            float* __restrict__ rec_part,
                            float* __restrict__ out_part,
                            int do_rec) {
    __shared__ __attribute__((aligned(16))) unsigned short As[128 * 32];
    __shared__ __attribute__((aligned(16))) unsigned short Bs[128 * 32];
    const int bid = blockIdx.x;
    const int tid = threadIdx.x;
    if (do_rec) {
        if (bid < 256)
            spk_tile_gemm(spk, WrecT, rec_part, N_HID, bid & 31, bid >> 5, As, Bs, tid);
        else {
            int o = bid - 256;
            spk_tile_gemm(spk, WoutT, out_part, N_OUT, o & 7, o >> 3, As, Bs, tid);
        }
    } else {
        spk_tile_gemm(spk, WoutT, out_part, N_OUT, bid & 7, bid >> 3, As, Bs, tid);
    }
}

// ---------------------------------------------------------------------------
// Transient pointwise step. grid = 512 (4 blocks per batch, quarter each),
// 256 threads. Thread (q,tid) owns t4 = q*256+tid: h cols 4*t4..4*t4+3 and
// o col t4 — elementwise identical math to the round-6 1024-thread version.
// ---------------------------------------------------------------------------
__global__ __launch_bounds__(256)
void transient_update_kernel(const float* __restrict__ inp,      // [B][Tc][N_HID]
                             const float* __restrict__ rec_part, // [KSPLIT][B][N_HID]
                             const float* __restrict__ out_part, // [KSPLIT][B][N_OUT]
                             float* __restrict__ h_mem,
                             float* __restrict__ o_mem,
                             unsigned short* __restrict__ spk,   // [B][N_HID] bf16
                             unsigned long long* __restrict__ maskg,
                             float* __restrict__ out,
                             int t_glob, int Tc, int has_rec, int has_out) {
    __shared__ __attribute__((aligned(16))) unsigned char spkb[256];
    const int b = blockIdx.x >> 2;
    const int q = blockIdx.x & 3;
    const int tid = threadIdx.x;
    const int t4 = q * 256 + tid;

    if (has_out) {
        float s = 0.f;
        #pragma unroll
        for (int ks = 0; ks < KSPLIT; ++ks)
            s += out_part[(size_t)ks * B_SZ * N_OUT + (size_t)b * N_OUT + t4];
        float o = TAU * o_mem[(size_t)b * N_OUT + t4] + s;
        o_mem[(size_t)b * N_OUT + t4] = o;
        out[((size_t)b * T_SZ + (t_glob - 1)) * N_OUT + t4] = o;
    }

    float rec[4] = {0.f, 0.f, 0.f, 0.f};
    if (has_rec) {
        #pragma unroll
        for (int ks = 0; ks < KSPLIT; ++ks) {
            float4 p = *(const float4*)(rec_part + (size_t)ks * B_SZ * N_HID
                                        + (size_t)b * N_HID + 4 * t4);
            rec[0] += p.x; rec[1] += p.y; rec[2] += p.z; rec[3] += p.w;
        }
    }

    unsigned short* sp = spk + (size_t)b * N_HID + 4 * t4;
    ush4 prev = *(const ush4*)sp;    // bf16 {0,1}; t_glob=0: h=0 so unused
    float4 iv = *(const float4*)(inp + ((size_t)b * Tc + t_glob) * N_HID + 4 * t4);
    float ivv[4] = {iv.x, iv.y, iv.z, iv.w};
    float* hp = h_mem + (size_t)b * N_HID + 4 * t4;
    float hv[4] = {hp[0], hp[1], hp[2], hp[3]};
    ush4 news;
    unsigned nib = 0;
    #pragma unroll
    for (int k = 0; k < 4; ++k) {
        float spf = bf2f(prev[k]);
        float v = TAU * hv[k] * (1.0f - spf) + (ivv[k] + REC_SCALE * rec[k]);
        hp[k] = v;
        bool s = (v >= THRESH);
        news[k] = s ? (unsigned short)0x3F80 : (unsigned short)0;
        nib |= (s ? 1u : 0u) << k;
    }
    *(ush4*)sp = news;
    spkb[tid] = (unsigned char)nib;
    __syncthreads();
    if (tid < 16) {
        uint4 qd = *(const uint4*)&spkb[tid * 16];
        unsigned w0 = pack4(qd.x) | (pack4(qd.y) << 16);
        unsigned w1 = pack4(qd.z) | (pack4(qd.w) << 16);
        maskg[b * 64 + q * 16 + tid] = (unsigned long long)w0
                                     | ((unsigned long long)w1 << 32);
    }
}

// ---------------------------------------------------------------------------
// min-side list build from a 64-bit word per lane (wave 0 only).
// ---------------------------------------------------------------------------
__device__ __forceinline__ void build_list_core(unsigned long long w,
                                                unsigned short* list,
                                                int* sh_n, int* sh_inact,
                                                int lane) {
    int tot = __builtin_popcountll(w);
    #pragma unroll
    for (int d = 32; d > 0; d >>= 1) tot += __shfl_xor(tot, d, 64);
    int inact = tot > (N_HID / 2);
    unsigned long long wsel = inact ? ~w : w;
    int c = __builtin_popcountll(wsel);
    int scan = c;
    #pragma unroll
    for (int d = 1; d < 64; d <<= 1) {
        int v = __shfl_up(scan, d, 64);
        if (lane >= d) scan += v;
    }
    int off = scan - c;
    while (wsel) {
        int bpos = __builtin_ctzll(wsel);
        list[off++] = (unsigned short)(lane * 64 + bpos);
        wsel &= wsel - 1;
    }
    if (lane == 0) {
        *sh_n = inact ? (N_HID - tot) : tot;
        *sh_inact = inact;
    }
}

// ---------------------------------------------------------------------------
// Sparse RSNN step loop for steps tloc0..tloc0+nsteps-1 of the current chunk.
// ---------------------------------------------------------------------------
__global__ __launch_bounds__(1024, 4)
void rsnn_step_kernel(const float* __restrict__ inp,            // [B][Tc][N_HID]
                      const unsigned short* __restrict__ WrecB, // [N_HID][N_HID] bf16
                      const unsigned short* __restrict__ WoutB, // [N_HID][N_OUT] bf16
                      const float* __restrict__ cs_rec,
                      const float* __restrict__ cs_out,
                      const float* __restrict__ out_part,       // [KSPLIT][B][N_OUT]
                      float* __restrict__ h_mem_g,
                      float* __restrict__ o_mem_g,
                      unsigned long long* __restrict__ mask_g,
                      float* __restrict__ out,
                      int t0, int Tc, int tloc0, int nsteps, int do_accum) {
    __shared__ unsigned long long mask[64];
    __shared__ __attribute__((aligned(16))) unsigned short list[N_HID];
    __shared__ __attribute__((aligned(16))) unsigned char spk[1024];
    __shared__ int sh_n;
    __shared__ int sh_inact;

    const int b = blockIdx.x;
    const int t = threadIdx.x;           // 0..1023
    const int lane = t & 63;
    const int wave = t >> 6;

    float hm[4], csr[4];
    #pragma unroll
    for (int k = 0; k < 4; ++k) {
        hm[k]  = h_mem_g[(size_t)b * N_HID + 4 * t + k];
        csr[k] = cs_rec[4 * t + k];
    }
    float om  = o_mem_g[(size_t)b * N_OUT + t];
    float cso = cs_out[t];
    if (do_accum) {
        float s = 0.f;
        #pragma unroll
        for (int ks = 0; ks < KSPLIT; ++ks)
            s += out_part[(size_t)ks * B_SZ * N_OUT + (size_t)b * N_OUT + t];
        om = TAU * om + s;
        out[((size_t)b * T_SZ + (t0 + tloc0 - 1)) * N_OUT + t] = om;
    }
    if (t < 64) mask[t] = mask_g[b * 64 + t];
    __syncthreads();

    // previous-step spike flags for cols 4t..4t+3 (hard reset term)
    float spf[4];
    {
        unsigned long long w = mask[t >> 4];
        int sh = 4 * (t & 15);
        #pragma unroll
        for (int k = 0; k < 4; ++k)
            spf[k] = (float)((w >> (sh + k)) & 1ULL);
    }
    if (wave == 0) build_list_core(mask[lane], list, &sh_n, &sh_inact, lane);
    __syncthreads();

    const unsigned short* Wb = WrecB + 4 * t;
    const unsigned short* Wo = WoutB + t;

    for (int tl = 0; tl < nsteps; ++tl) {
        // ---- recurrent gather over min side of previous spikes ----
        int n = sh_n, inact = sh_inact;
        float a[8][4] = {};
        int i = 0;
        for (; i + 8 <= n; i += 8) {
            ush8 jv = *(const ush8*)&list[i];
            #pragma unroll
            for (int r = 0; r < 8; ++r) {
                uint2 v = *(const uint2*)(Wb + (size_t)jv[r] * N_HID);
                a[r][0] += __uint_as_float(v.x << 16);
                a[r][1] += __uint_as_float(v.x & 0xFFFF0000u);
                a[r][2] += __uint_as_float(v.y << 16);
                a[r][3] += __uint_as_float(v.y & 0xFFFF0000u);
            }
        }
        for (; i < n; ++i) {
            uint2 v = *(const uint2*)(Wb + (size_t)list[i] * N_HID);
            a[0][0] += __uint_as_float(v.x << 16);
            a[0][1] += __uint_as_float(v.x & 0xFFFF0000u);
            a[0][2] += __uint_as_float(v.y << 16);
            a[0][3] += __uint_as_float(v.y & 0xFFFF0000u);
        }
        float racc[4];
        #pragma unroll
        for (int k = 0; k < 4; ++k)
            racc[k] = ((a[0][k] + a[1][k]) + (a[2][k] + a[3][k]))
                    + ((a[4][k] + a[5][k]) + (a[6][k] + a[7][k]));

        float4 iv = *(const float4*)(inp + ((size_t)b * Tc + tloc0 + tl) * N_HID + 4 * t);
        float ivv[4] = {iv.x, iv.y, iv.z, iv.w};
        unsigned nib = 0;
        #pragma unroll
        for (int k = 0; k < 4; ++k) {
            float rec = REC_SCALE * (inact ? (csr[k] - racc[k]) : racc[k]);
            float v = TAU * hm[k] * (1.0f - spf[k]) + (ivv[k] + rec);
            hm[k] = v;
            bool s = (v >= THRESH);
            spf[k] = s ? 1.0f : 0.0f;
            nib |= (s ? 1u : 0u) << k;
        }
        __syncthreads();            // all list readers done before overwrite
        spk[t] = (unsigned char)nib;
        __syncthreads();            // spk visible to wave 0
        if (wave == 0) {
            uint4 q = *(const uint4*)&spk[lane * 16];
            unsigned w0 = pack4(q.x) | (pack4(q.y) << 16);
            unsigned w1 = pack4(q.z) | (pack4(q.w) << 16);
            unsigned long long w = (unsigned long long)w0
                                 | ((unsigned long long)w1 << 32);
            mask[lane] = w;
            build_list_core(w, list, &sh_n, &sh_inact, lane);
        }
        __syncthreads();            // list/counts ready

        // ---- output gather over min side of NEW spikes ----
        int n2 = sh_n; inact = sh_inact;
        float o8[8] = {};
        i = 0;
        for (; i + 16 <= n2; i += 16) {
            ush8 j0 = *(const ush8*)&list[i];
            ush8 j1 = *(const ush8*)&list[i + 8];
            #pragma unroll
            for (int r = 0; r < 8; ++r) o8[r] += bf2f(Wo[(size_t)j0[r] * N_OUT]);
            #pragma unroll
            for (int r = 0; r < 8; ++r) o8[r] += bf2f(Wo[(size_t)j1[r] * N_OUT]);
        }
        for (; i + 8 <= n2; i += 8) {
            ush8 j0 = *(const ush8*)&list[i];
            #pragma unroll
            for (int r = 0; r < 8; ++r) o8[r] += bf2f(Wo[(size_t)j0[r] * N_OUT]);
        }
        for (; i < n2; ++i) o8[0] += bf2f(Wo[(size_t)list[i] * N_OUT]);
        float oacc = ((o8[0] + o8[1]) + (o8[2] + o8[3]))
                   + ((o8[4] + o8[5]) + (o8[6] + o8[7]));
        float contrib = inact ? (cso - oacc) : oacc;
        om = TAU * om + contrib;
        out[((size_t)b * T_SZ + (t0 + tloc0 + tl)) * N_OUT + t] = om;
    }

    #pragma unroll
    for (int k = 0; k < 4; ++k)
        h_mem_g[(size_t)b * N_HID + 4 * t + k] = hm[k];
    o_mem_g[(size_t)b * N_OUT + t] = om;
    __syncthreads();
    if (t < 64) mask_g[b * 64 + t] = mask[t];
}

// ---------------------------------------------------------------------------
extern "C" void kernel_launch(void* const* d_in, const int* in_sizes, int n_in,
                              void* d_out, int out_size, void* d_ws, size_t ws_size,
                              hipStream_t stream) {
    const float* x    = (const float*)d_in[0];
    const float* Wfc1 = (const float*)d_in[1];
    const float* Wrec = (const float*)d_in[2];
    const float* Wout = (const float*)d_in[3];
    float* out = (float*)d_out;

    // workspace layout (all 16B-aligned)
    float* h_mem = (float*)d_ws;                               // 2 MB
    float* o_mem = h_mem + B_SZ * N_HID;                       // 0.5 MB
    unsigned long long* maskg =
        (unsigned long long*)(o_mem + B_SZ * N_OUT);           // 64 KB
    float* cs_rec = (float*)(maskg + B_SZ * 64);               // 16 KB
    float* cs_out = cs_rec + N_HID;                            // 4 KB
    unsigned short* WrecB = (unsigned short*)(cs_out + N_OUT); // 33.55 MB
    unsigned short* WoutB = WrecB + (size_t)N_HID * N_HID;     // 8.39 MB
    unsigned short* WrecT = WoutB + (size_t)N_HID * N_OUT;     // 33.55 MB
    unsigned short* WoutT = WrecT + (size_t)N_HID * N_HID;     // 8.39 MB
    unsigned short* Bt    = WoutT + (size_t)N_OUT * N_HID;     // 16.78 MB
    unsigned short* spk   = Bt + (size_t)N_HID * 2048;         // 1.05 MB
    float* rec_part = (float*)(spk + (size_t)B_SZ * N_HID);    // 16.78 MB
    float* out_part = rec_part + (size_t)KSPLIT * B_SZ * N_HID;// 4.19 MB
    unsigned short* Ax = (unsigned short*)(out_part + (size_t)KSPLIT * B_SZ * N_OUT);
    // inp_chunk follows Ax (Tc-dependent)

    size_t fixed_bytes = (size_t)(B_SZ * N_HID + B_SZ * N_OUT) * 4
                       + (size_t)B_SZ * 64 * 8
                       + (size_t)(N_HID + N_OUT) * 4
                       + 2 * (size_t)N_HID * N_HID * 2          // WrecB + WrecT
                       + 2 * (size_t)N_HID * N_OUT * 2          // WoutB + WoutT
                       + (size_t)N_HID * 2048 * 2               // Bt
                       + (size_t)B_SZ * N_HID * 2               // spk
                       + (size_t)KSPLIT * B_SZ * (N_HID + N_OUT) * 4;
    int Tc = 64;
    while (Tc > 8 &&
           fixed_bytes + (size_t)Tc * (B_SZ * 2048 * 2 + B_SZ * N_HID * 4) > ws_size)
        Tc >>= 1;
    float* inp_chunk = (float*)(Ax + (size_t)B_SZ * Tc * 2048);

    int state_floats = B_SZ * N_HID + B_SZ * N_OUT + B_SZ * 64 * 2;
    zero_state_kernel<<<256, 256, 0, stream>>>(h_mem, state_floats);
    // fused bf16 copy + transpose (one read of each weight matrix)
    convT_bf16_kernel<<<dim3(N_HID / 64, N_HID / 64), 256, 0, stream>>>(
        Wrec, WrecB, WrecT, N_HID, N_HID);
    convT_bf16_kernel<<<dim3(N_OUT / 64, N_HID / 64), 256, 0, stream>>>(
        Wout, WoutB, WoutT, N_HID, N_OUT);
    colsum_bf16_kernel<<<80, 256, 0, stream>>>(WrecB, WoutB, cs_rec, cs_out);
    convert_w_kernel<<<dim3(32, 64), 256, 0, stream>>>(Wfc1, Bt);

    for (int t0 = 0; t0 < T_SZ; t0 += Tc) {
        convert_x_kernel<<<2048, 256, 0, stream>>>(x, Ax, t0, Tc);
        fc1_mfma_kernel<<<dim3(N_HID / 128, Tc), 256, 0, stream>>>(Ax, Bt, inp_chunk);

        if (t0 == 0) {
            // dense transient: steps 0..S_DENSE-1, two dispatches per step
            for (int tg = 0; tg < S_DENSE; ++tg) {
                transient_update_kernel<<<B_SZ * 4, 256, 0, stream>>>(
                    inp_chunk, rec_part, out_part, h_mem, o_mem, spk, maskg, out,
                    tg, Tc, /*has_rec=*/tg > 0, /*has_out=*/tg > 0);
                int do_rec = (tg + 1 < S_DENSE);
                spk_gemm_merged_kernel<<<do_rec ? 320 : 64, 256, 0, stream>>>(
                    spk, WrecT, WoutT, rec_part, out_part, do_rec);
            }
            rsnn_step_kernel<<<B_SZ, 1024, 0, stream>>>(
                inp_chunk, WrecB, WoutB, cs_rec, cs_out, out_part,
                h_mem, o_mem, maskg, out,
                t0, Tc, /*tloc0=*/S_DENSE, /*nsteps=*/Tc - S_DENSE, /*do_accum=*/1);
        } else {
            rsnn_step_kernel<<<B_SZ, 1024, 0, stream>>>(
                inp_chunk, WrecB, WoutB, cs_rec, cs_out, out_part,
                h_mem, o_mem, maskg, out,
                t0, Tc, /*tloc0=*/0, /*nsteps=*/Tc, /*do_accum=*/0);
        }
    }
}